// Round 17
// baseline (452.207 us; speedup 1.0000x reference)
//
#include <hip/hip_runtime.h>
#include <hip/hip_bf16.h>

// ---------------------------------------------------------------------------
// Fused MLP+LSTM for B=131072 rows, v11 (4th submit — infra failures x3) =
// v6 shell + v8 spill-free body.
// 1024-thread blocks (16 waves, 4 waves/SIMD, 128 unified regs/wave),
// grid = 256 = 1 block/CU. ALL four fat weight layers in 144 KB LDS (staged
// once). Each wave runs 2 sequential 16-row chains (512 rows/block).
// Chain body is v8's proven no-spill structure: x pair-streamed in L1
// (2 loads in flight, static indices), h0/c0 deferred to L1c, acc <=32 AGPR.
// Operand-swapped MFMA chain: D = W*act^T keeps batch row at lane&15.
// ---------------------------------------------------------------------------

typedef __bf16 bf16x8 __attribute__((ext_vector_type(8)));
typedef float  f32x4  __attribute__((ext_vector_type(4)));
typedef int    i32x4  __attribute__((ext_vector_type(4)));

#define MFMA16(A, B, C) __builtin_amdgcn_mfma_f32_16x16x32_bf16((A), (B), (C), 0, 0, 0)

// fragment-element offsets (bf16 elems). [0, LDS_ELEMS) staged to LDS.
#define WOFF_FC1    0
#define WOFF_FC1A_H 32768
#define WOFF_FC1B   49152
#define WOFF_FC1C   65536
#define LDS_ELEMS   73728          // 147456 B = 144 KB
#define WOFF_FC1A_W 73728
#define WOFF_FC2    81920
#define WOFF_FC3    83968
#define WOFF_WIH    84992
#define WOFF_WHH    89088
#define WOFF_FC4    93184
#define WTOT        94208
// bias offsets (floats, after bf16 region in ws)
#define BOFF_FC1  0
#define BOFF_FC1A 128
#define BOFF_FC1B 256
#define BOFF_FC1C 384
#define BOFF_FC2  448
#define BOFF_FC3  480
#define BOFF_LSTM 512
#define BOFF_FC4  640
#define BTOT      672

// ---------------------------------------------------------------------------
// Fragment mapping (verified since v1):
//   rel -> j = rel&7, lane = (rel>>3)&63, fs = rel>>9, s = fs%ns, t = fs/ns,
//   gq = lane>>4, n = 16t + (lane&15),
//   k = perm ? 16*(2s + (j>>2)) + 4*gq + (j&3) : 32*s + 8*gq + j
// ---------------------------------------------------------------------------
__device__ __forceinline__ void conv_frag(int rel, const float* __restrict__ src,
                                          __bf16* __restrict__ dst,
                                          int ns, int Krow, int kbase, int klim, int perm) {
    int j    = rel & 7;
    int lane = (rel >> 3) & 63;
    int fs   = rel >> 9;
    int s    = fs % ns;
    int t    = fs / ns;
    int gq   = lane >> 4;
    int n    = 16 * t + (lane & 15);
    int k    = perm ? (16 * (2 * s + (j >> 2)) + 4 * gq + (j & 3))
                    : (32 * s + 8 * gq + j);
    float v  = (k < klim) ? src[n * Krow + kbase + k] : 0.f;
    dst[rel] = (__bf16)v;
}

// ---------------------------------------------------------------------------
// Prep: full fp32 -> bf16 fragment conversion + bias folding (runs once).
// ---------------------------------------------------------------------------
__global__ void prep_kernel(const float* __restrict__ fc1w,  const float* __restrict__ fc1b,
                            const float* __restrict__ fc1aw, const float* __restrict__ fc1ab,
                            const float* __restrict__ fc1bw, const float* __restrict__ fc1bb,
                            const float* __restrict__ wgame, const float* __restrict__ fc1cw,
                            const float* __restrict__ fc1cb, const float* __restrict__ fc2w,
                            const float* __restrict__ fc2b,  const float* __restrict__ fc3w,
                            const float* __restrict__ fc3b,  const float* __restrict__ wih,
                            const float* __restrict__ whh,   const float* __restrict__ bih,
                            const float* __restrict__ bhh,   const float* __restrict__ fc4w,
                            const float* __restrict__ fc4b,
                            __bf16* __restrict__ wsw, float* __restrict__ wsb) {
    int idx = blockIdx.x * 256 + threadIdx.x;
    if (idx < WTOT) {
        if      (idx < WOFF_FC1A_H) conv_frag(idx - WOFF_FC1,    fc1w,  wsw + WOFF_FC1,    8, 256,   0, 256, 0);
        else if (idx < WOFF_FC1B)   conv_frag(idx - WOFF_FC1A_H, fc1aw, wsw + WOFF_FC1A_H, 4, 164,   0, 128, 1);
        else if (idx < WOFF_FC1C)   conv_frag(idx - WOFF_FC1B,   fc1bw, wsw + WOFF_FC1B,   4, 128,   0, 128, 1);
        else if (idx < WOFF_FC1A_W) conv_frag(idx - WOFF_FC1C,   fc1cw, wsw + WOFF_FC1C,   4, 140,   0, 128, 1);
        else if (idx < WOFF_FC2)    conv_frag(idx - WOFF_FC1A_W, fc1aw, wsw + WOFF_FC1A_W, 2, 164, 128,  36, 0);
        else if (idx < WOFF_FC3)    conv_frag(idx - WOFF_FC2,    fc2w,  wsw + WOFF_FC2,    2,  64,   0,  64, 1);
        else if (idx < WOFF_WIH)    conv_frag(idx - WOFF_FC3,    fc3w,  wsw + WOFF_FC3,    1,  32,   0,  32, 1);
        else if (idx < WOFF_WHH)    conv_frag(idx - WOFF_WIH,    wih,   wsw + WOFF_WIH,    1,  32,   0,  32, 1);
        else if (idx < WOFF_FC4)    conv_frag(idx - WOFF_WHH,    whh,   wsw + WOFF_WHH,    1,  32,   0,  32, 0);
        else                        conv_frag(idx - WOFF_FC4,    fc4w,  wsw + WOFF_FC4,    1,  32,   0,  32, 1);
    } else if (idx < WTOT + BTOT) {
        int bi = idx - WTOT;
        float v;
        if      (bi < 128) v = fc1b[bi];
        else if (bi < 256) v = fc1ab[bi - 128];
        else if (bi < 384) v = fc1bb[bi - 256];
        else if (bi < 448) {            // fold fc1c_w[:,128:140] @ w_game into bias
            int n = bi - 384;
            v = fc1cb[n];
            for (int q = 0; q < 12; ++q) v += fc1cw[n * 140 + 128 + q] * wgame[q];
        }
        else if (bi < 480) v = fc2b[bi - 448];
        else if (bi < 512) v = fc3b[bi - 480];
        else if (bi < 640) { int n = bi - 512; v = bih[n] + bhh[n]; }   // fused LSTM bias
        else               v = fc4b[bi - 640];
        wsb[bi] = v;
    }
}

// ---------------------------------------------------------------------------
// Helpers
// ---------------------------------------------------------------------------
__device__ __forceinline__ bf16x8 ld8f(const float* __restrict__ p) {
    f32x4 a = *(const f32x4*)p;
    f32x4 b = *(const f32x4*)(p + 4);
    bf16x8 r;
    r[0] = (__bf16)a[0]; r[1] = (__bf16)a[1]; r[2] = (__bf16)a[2]; r[3] = (__bf16)a[3];
    r[4] = (__bf16)b[0]; r[5] = (__bf16)b[1]; r[6] = (__bf16)b[2]; r[7] = (__bf16)b[3];
    return r;
}

__device__ __forceinline__ bf16x8 ld4f_masked(const float* __restrict__ p, bool on) {
    f32x4 v = {0.f, 0.f, 0.f, 0.f};
    if (on) v = *(const f32x4*)p;
    bf16x8 r;
    r[0] = (__bf16)v[0]; r[1] = (__bf16)v[1]; r[2] = (__bf16)v[2]; r[3] = (__bf16)v[3];
    r[4] = (__bf16)0.f;  r[5] = (__bf16)0.f;  r[6] = (__bf16)0.f;  r[7] = (__bf16)0.f;
    return r;
}

// pack acc[2s],acc[2s+1] (n = 16t+4g+r) into next-layer B-frag, with relu
__device__ __forceinline__ bf16x8 packrelu(const f32x4* a, int s) {
    bf16x8 r;
#pragma unroll
    for (int j = 0; j < 8; ++j) {
        float v = a[2 * s + (j >> 2)][j & 3];
        r[j] = (__bf16)fmaxf(v, 0.f);
    }
    return r;
}

__device__ __forceinline__ float sigm(float v)  { return 1.f / (1.f + __expf(-v)); }
__device__ __forceinline__ float tanh_(float v) { return 1.f - 2.f / (1.f + __expf(2.f * v)); }

// ---------------------------------------------------------------------------
// Chain body (v8-proven): one 16-row chain for `row`, writes out[rowbase..+16)
// ---------------------------------------------------------------------------
__device__ __forceinline__ void run_chain(
        int rowbase, int lane, int gq, int mr,
        const float* __restrict__ x,  const float* __restrict__ w,
        const float* __restrict__ h0, const float* __restrict__ c0,
        const float* __restrict__ fc5w, const float* __restrict__ fc5b,
        const __bf16* __restrict__ slds, const __bf16* __restrict__ wsw,
        const float* __restrict__ wsb, float* __restrict__ out) {
    const int row = rowbase + mr;

    const bf16x8* Wfc1  = (const bf16x8*)(slds + WOFF_FC1);
    const bf16x8* Wf1aH = (const bf16x8*)(slds + WOFF_FC1A_H);
    const bf16x8* Wfc1b = (const bf16x8*)(slds + WOFF_FC1B);
    const bf16x8* Wfc1c = (const bf16x8*)(slds + WOFF_FC1C);
    const bf16x8* Wf1aW = (const bf16x8*)(wsw + WOFF_FC1A_W);
    const bf16x8* Wfc2  = (const bf16x8*)(wsw + WOFF_FC2);
    const bf16x8* Wfc3  = (const bf16x8*)(wsw + WOFF_FC3);
    const bf16x8* Wwih  = (const bf16x8*)(wsw + WOFF_WIH);
    const bf16x8* Wwhh  = (const bf16x8*)(wsw + WOFF_WHH);
    const bf16x8* Wfc4  = (const bf16x8*)(wsw + WOFF_FC4);

    // ---- L1: x[256] -> h1[128]  (x pair-streamed, 2 loads in flight) ------
    bf16x8 h1f[4];
    {
        f32x4 acc1[8];
#pragma unroll
        for (int t = 0; t < 8; ++t)
            acc1[t] = *(const f32x4*)(wsb + BOFF_FC1 + 16 * t + 4 * gq);
        const float* xrow = x + row * 256 + 8 * gq;
#pragma unroll
        for (int p = 0; p < 4; ++p) {
            bf16x8 a0 = ld8f(xrow + 64 * p);
            bf16x8 a1 = ld8f(xrow + 64 * p + 32);
#pragma unroll
            for (int t = 0; t < 8; ++t)
                acc1[t] = MFMA16(Wfc1[(t * 8 + 2 * p) * 64 + lane], a0, acc1[t]);
#pragma unroll
            for (int t = 0; t < 8; ++t)
                acc1[t] = MFMA16(Wfc1[(t * 8 + 2 * p + 1) * 64 + lane], a1, acc1[t]);
        }
#pragma unroll
        for (int s = 0; s < 4; ++s) h1f[s] = packrelu(acc1, s);
    }

    // ---- L1a: [h1, w] (128+36) -> h2[128] --------------------------------
    bf16x8 h2f[4];
    {
        bf16x8 wxa0 = ld8f(w + row * 36 + 8 * gq);
        bf16x8 wxa1 = ld4f_masked(w + row * 36 + 32, gq == 0);
        f32x4 acc2[8];
#pragma unroll
        for (int t = 0; t < 8; ++t)
            acc2[t] = *(const f32x4*)(wsb + BOFF_FC1A + 16 * t + 4 * gq);
#pragma unroll
        for (int s = 0; s < 4; ++s)
#pragma unroll
            for (int t = 0; t < 8; ++t)
                acc2[t] = MFMA16(Wf1aH[(t * 4 + s) * 64 + lane], h1f[s], acc2[t]);
#pragma unroll
        for (int t = 0; t < 8; ++t) {
            acc2[t] = MFMA16(Wf1aW[(t * 2 + 0) * 64 + lane], wxa0, acc2[t]);
            acc2[t] = MFMA16(Wf1aW[(t * 2 + 1) * 64 + lane], wxa1, acc2[t]);
        }
#pragma unroll
        for (int s = 0; s < 4; ++s) h2f[s] = packrelu(acc2, s);
    }

    // ---- L1b: h2[128] -> h3[128] -----------------------------------------
    bf16x8 h3f[4];
    {
        f32x4 acc3[8];
#pragma unroll
        for (int t = 0; t < 8; ++t)
            acc3[t] = *(const f32x4*)(wsb + BOFF_FC1B + 16 * t + 4 * gq);
#pragma unroll
        for (int s = 0; s < 4; ++s)
#pragma unroll
            for (int t = 0; t < 8; ++t)
                acc3[t] = MFMA16(Wfc1b[(t * 4 + s) * 64 + lane], h2f[s], acc3[t]);
#pragma unroll
        for (int s = 0; s < 4; ++s) h3f[s] = packrelu(acc3, s);
    }

    // LSTM-state inputs: needed 2 layers from here; issue now
    bf16x8 h0f  = ld8f(h0 + row * 32 + 8 * gq);
    f32x4  c0r0 = *(const f32x4*)(c0 + row * 32 + 4 * gq);
    f32x4  c0r1 = *(const f32x4*)(c0 + row * 32 + 16 + 4 * gq);

    // ---- L1c: [h3, w_game] -> h4[64]  (w_game folded into bias) ----------
    bf16x8 h4f[2];
    {
        f32x4 acc4[4];
#pragma unroll
        for (int t = 0; t < 4; ++t)
            acc4[t] = *(const f32x4*)(wsb + BOFF_FC1C + 16 * t + 4 * gq);
#pragma unroll
        for (int s = 0; s < 4; ++s)
#pragma unroll
            for (int t = 0; t < 4; ++t)
                acc4[t] = MFMA16(Wfc1c[(t * 4 + s) * 64 + lane], h3f[s], acc4[t]);
#pragma unroll
        for (int s = 0; s < 2; ++s) h4f[s] = packrelu(acc4, s);
    }

    // ---- L2: h4[64] -> h5[32] --------------------------------------------
    bf16x8 h5f;
    {
        f32x4 acc5[2];
#pragma unroll
        for (int t = 0; t < 2; ++t)
            acc5[t] = *(const f32x4*)(wsb + BOFF_FC2 + 16 * t + 4 * gq);
#pragma unroll
        for (int s = 0; s < 2; ++s)
#pragma unroll
            for (int t = 0; t < 2; ++t)
                acc5[t] = MFMA16(Wfc2[(t * 2 + s) * 64 + lane], h4f[s], acc5[t]);
        h5f = packrelu(acc5, 0);
    }

    // ---- L3: h5[32] -> h6[32] --------------------------------------------
    bf16x8 h6f;
    {
        f32x4 acc6[2];
#pragma unroll
        for (int t = 0; t < 2; ++t)
            acc6[t] = *(const f32x4*)(wsb + BOFF_FC3 + 16 * t + 4 * gq);
#pragma unroll
        for (int t = 0; t < 2; ++t)
            acc6[t] = MFMA16(Wfc3[t * 64 + lane], h5f, acc6[t]);
        h6f = packrelu(acc6, 0);
    }

    // ---- LSTM gates ------------------------------------------------------
    bf16x8 hnf;
    {
        f32x4 accg[8];
#pragma unroll
        for (int t = 0; t < 8; ++t)
            accg[t] = *(const f32x4*)(wsb + BOFF_LSTM + 16 * t + 4 * gq);
#pragma unroll
        for (int t = 0; t < 8; ++t)
            accg[t] = MFMA16(Wwih[t * 64 + lane], h6f, accg[t]);
#pragma unroll
        for (int t = 0; t < 8; ++t)
            accg[t] = MFMA16(Wwhh[t * 64 + lane], h0f, accg[t]);
        // gate tiles: i -> {0,1}, f -> {2,3}, g -> {4,5}, o -> {6,7}
#pragma unroll
        for (int t2 = 0; t2 < 2; ++t2) {
            f32x4 cc = t2 ? c0r1 : c0r0;
#pragma unroll
            for (int r = 0; r < 4; ++r) {
                float ig = accg[t2][r];
                float fg = accg[2 + t2][r];
                float gg = accg[4 + t2][r];
                float og = accg[6 + t2][r];
                float cn = sigm(fg) * cc[r] + sigm(ig) * tanh_(gg);
                hnf[t2 * 4 + r] = (__bf16)(sigm(og) * tanh_(cn));
            }
        }
    }

    // ---- L4: h_new[32] -> o1[32] -----------------------------------------
    f32x4 acco[2];
#pragma unroll
    for (int t = 0; t < 2; ++t)
        acco[t] = *(const f32x4*)(wsb + BOFF_FC4 + 16 * t + 4 * gq);
#pragma unroll
    for (int t = 0; t < 2; ++t)
        acco[t] = MFMA16(Wfc4[t * 64 + lane], hnf, acco[t]);

    // ---- L5 + sigmoid ----------------------------------------------------
    f32x4 w5a = *(const f32x4*)(fc5w + 4 * gq);
    f32x4 w5b = *(const f32x4*)(fc5w + 16 + 4 * gq);
    float p = 0.f;
#pragma unroll
    for (int r = 0; r < 4; ++r) {
        p += fmaxf(acco[0][r], 0.f) * w5a[r];
        p += fmaxf(acco[1][r], 0.f) * w5b[r];
    }
    p += __shfl_xor(p, 16);
    p += __shfl_xor(p, 32);
    float res = sigm(p + fc5b[0]);
    if (lane < 16) out[rowbase + lane] = res;
}

// ---------------------------------------------------------------------------
// Fused main kernel: 16 waves/block, 2 sequential 16-row chains, 512 rows/blk
// ---------------------------------------------------------------------------
__global__ __launch_bounds__(1024, 4) void fused_mlp_lstm(
        const float* __restrict__ x,  const float* __restrict__ w,
        const float* __restrict__ h0, const float* __restrict__ c0,
        const float* __restrict__ fc5w, const float* __restrict__ fc5b,
        const __bf16* __restrict__ wsw, const float* __restrict__ wsb,
        float* __restrict__ out) {
    __shared__ __align__(16) __bf16 slds[LDS_ELEMS];   // 144 KB

    const int tid  = threadIdx.x;
    const int lane = tid & 63;
    const int gq   = lane >> 4;
    const int mr   = lane & 15;
    const int rowbase0 = blockIdx.x * 512 + (tid >> 6) * 16;

    // ---- stage all big weight layers to LDS (9 x 16B per thread) ----------
    {
        const i32x4* gs = (const i32x4*)wsw;
        i32x4*       sd = (i32x4*)slds;
#pragma unroll
        for (int i = 0; i < 9; ++i) sd[i * 1024 + tid] = gs[i * 1024 + tid];
    }
    __syncthreads();

    run_chain(rowbase0,       lane, gq, mr, x, w, h0, c0, fc5w, fc5b, slds, wsw, wsb, out);
    run_chain(rowbase0 + 256, lane, gq, mr, x, w, h0, c0, fc5w, fc5b, slds, wsw, wsb, out);
}

// ---------------------------------------------------------------------------
extern "C" void kernel_launch(void* const* d_in, const int* in_sizes, int n_in,
                              void* d_out, int out_size, void* d_ws, size_t ws_size,
                              hipStream_t stream) {
    const float* x     = (const float*)d_in[0];
    const float* w     = (const float*)d_in[1];
    const float* h0    = (const float*)d_in[2];
    const float* c0    = (const float*)d_in[3];
    const float* fc1w  = (const float*)d_in[4];
    const float* fc1b  = (const float*)d_in[5];
    const float* fc1aw = (const float*)d_in[6];
    const float* fc1ab = (const float*)d_in[7];
    const float* fc1bw = (const float*)d_in[8];
    const float* fc1bb = (const float*)d_in[9];
    const float* wgame = (const float*)d_in[10];
    const float* fc1cw = (const float*)d_in[11];
    const float* fc1cb = (const float*)d_in[12];
    const float* fc2w  = (const float*)d_in[13];
    const float* fc2b  = (const float*)d_in[14];
    const float* fc3w  = (const float*)d_in[15];
    const float* fc3b  = (const float*)d_in[16];
    const float* wih   = (const float*)d_in[17];
    const float* whh   = (const float*)d_in[18];
    const float* bih   = (const float*)d_in[19];
    const float* bhh   = (const float*)d_in[20];
    const float* fc4w  = (const float*)d_in[21];
    const float* fc4b  = (const float*)d_in[22];
    const float* fc5w  = (const float*)d_in[23];
    const float* fc5b  = (const float*)d_in[24];

    __bf16* wsw = (__bf16*)d_ws;
    float*  wsb = (float*)((char*)d_ws + WTOT * sizeof(__bf16));
    (void)ws_size; (void)n_in; (void)out_size;

    const int Btot = in_sizes[0] / 256;   // 131072 rows

    prep_kernel<<<(WTOT + BTOT + 255) / 256, 256, 0, stream>>>(
        fc1w, fc1b, fc1aw, fc1ab, fc1bw, fc1bb, wgame, fc1cw, fc1cb,
        fc2w, fc2b, fc3w, fc3b, wih, whh, bih, bhh, fc4w, fc4b, wsw, wsb);

    fused_mlp_lstm<<<Btot / 512, 1024, 0, stream>>>(
        x, w, h0, c0, fc5w, fc5b, wsw, wsb, (float*)d_out);
}

// Round 18
// 61.376 us; speedup vs baseline: 7.3678x; 7.3678x over previous
//
#include <hip/hip_runtime.h>
#include <hip/hip_bf16.h>

// ---------------------------------------------------------------------------
// Fused MLP+LSTM for B=131072 rows, v12.
// 1024-thread blocks (16 waves, 4 waves/SIMD, 128 unified regs/wave),
// ONE 16-row chain per wave (256 rows/block), grid = 512 (2 blocks/CU
// sequential; LDS restaging cost ~2 us total). ALL four fat weight layers
// in 144 KB LDS. Chain body is v8's proven no-spill structure verbatim:
// x pair-streamed in L1 (2 loads in flight, static indices), h0/c0 deferred
// to L1c, acc <=32 AGPR, all loops static. No multi-chain body -> no
// cross-chain register hoisting (v11's 873 MB spill).
// Operand-swapped MFMA chain: D = W*act^T keeps batch row at lane&15.
// ---------------------------------------------------------------------------

typedef __bf16 bf16x8 __attribute__((ext_vector_type(8)));
typedef float  f32x4  __attribute__((ext_vector_type(4)));
typedef int    i32x4  __attribute__((ext_vector_type(4)));

#define MFMA16(A, B, C) __builtin_amdgcn_mfma_f32_16x16x32_bf16((A), (B), (C), 0, 0, 0)

// fragment-element offsets (bf16 elems). [0, LDS_ELEMS) staged to LDS.
#define WOFF_FC1    0
#define WOFF_FC1A_H 32768
#define WOFF_FC1B   49152
#define WOFF_FC1C   65536
#define LDS_ELEMS   73728          // 147456 B = 144 KB
#define WOFF_FC1A_W 73728
#define WOFF_FC2    81920
#define WOFF_FC3    83968
#define WOFF_WIH    84992
#define WOFF_WHH    89088
#define WOFF_FC4    93184
#define WTOT        94208
// bias offsets (floats, after bf16 region in ws)
#define BOFF_FC1  0
#define BOFF_FC1A 128
#define BOFF_FC1B 256
#define BOFF_FC1C 384
#define BOFF_FC2  448
#define BOFF_FC3  480
#define BOFF_LSTM 512
#define BOFF_FC4  640
#define BTOT      672

// ---------------------------------------------------------------------------
// Fragment mapping (verified since v1):
//   rel -> j = rel&7, lane = (rel>>3)&63, fs = rel>>9, s = fs%ns, t = fs/ns,
//   gq = lane>>4, n = 16t + (lane&15),
//   k = perm ? 16*(2s + (j>>2)) + 4*gq + (j&3) : 32*s + 8*gq + j
// ---------------------------------------------------------------------------
__device__ __forceinline__ void conv_frag(int rel, const float* __restrict__ src,
                                          __bf16* __restrict__ dst,
                                          int ns, int Krow, int kbase, int klim, int perm) {
    int j    = rel & 7;
    int lane = (rel >> 3) & 63;
    int fs   = rel >> 9;
    int s    = fs % ns;
    int t    = fs / ns;
    int gq   = lane >> 4;
    int n    = 16 * t + (lane & 15);
    int k    = perm ? (16 * (2 * s + (j >> 2)) + 4 * gq + (j & 3))
                    : (32 * s + 8 * gq + j);
    float v  = (k < klim) ? src[n * Krow + kbase + k] : 0.f;
    dst[rel] = (__bf16)v;
}

// ---------------------------------------------------------------------------
// Prep: full fp32 -> bf16 fragment conversion + bias folding (runs once).
// ---------------------------------------------------------------------------
__global__ void prep_kernel(const float* __restrict__ fc1w,  const float* __restrict__ fc1b,
                            const float* __restrict__ fc1aw, const float* __restrict__ fc1ab,
                            const float* __restrict__ fc1bw, const float* __restrict__ fc1bb,
                            const float* __restrict__ wgame, const float* __restrict__ fc1cw,
                            const float* __restrict__ fc1cb, const float* __restrict__ fc2w,
                            const float* __restrict__ fc2b,  const float* __restrict__ fc3w,
                            const float* __restrict__ fc3b,  const float* __restrict__ wih,
                            const float* __restrict__ whh,   const float* __restrict__ bih,
                            const float* __restrict__ bhh,   const float* __restrict__ fc4w,
                            const float* __restrict__ fc4b,
                            __bf16* __restrict__ wsw, float* __restrict__ wsb) {
    int idx = blockIdx.x * 256 + threadIdx.x;
    if (idx < WTOT) {
        if      (idx < WOFF_FC1A_H) conv_frag(idx - WOFF_FC1,    fc1w,  wsw + WOFF_FC1,    8, 256,   0, 256, 0);
        else if (idx < WOFF_FC1B)   conv_frag(idx - WOFF_FC1A_H, fc1aw, wsw + WOFF_FC1A_H, 4, 164,   0, 128, 1);
        else if (idx < WOFF_FC1C)   conv_frag(idx - WOFF_FC1B,   fc1bw, wsw + WOFF_FC1B,   4, 128,   0, 128, 1);
        else if (idx < WOFF_FC1A_W) conv_frag(idx - WOFF_FC1C,   fc1cw, wsw + WOFF_FC1C,   4, 140,   0, 128, 1);
        else if (idx < WOFF_FC2)    conv_frag(idx - WOFF_FC1A_W, fc1aw, wsw + WOFF_FC1A_W, 2, 164, 128,  36, 0);
        else if (idx < WOFF_FC3)    conv_frag(idx - WOFF_FC2,    fc2w,  wsw + WOFF_FC2,    2,  64,   0,  64, 1);
        else if (idx < WOFF_WIH)    conv_frag(idx - WOFF_FC3,    fc3w,  wsw + WOFF_FC3,    1,  32,   0,  32, 1);
        else if (idx < WOFF_WHH)    conv_frag(idx - WOFF_WIH,    wih,   wsw + WOFF_WIH,    1,  32,   0,  32, 1);
        else if (idx < WOFF_FC4)    conv_frag(idx - WOFF_WHH,    whh,   wsw + WOFF_WHH,    1,  32,   0,  32, 0);
        else                        conv_frag(idx - WOFF_FC4,    fc4w,  wsw + WOFF_FC4,    1,  32,   0,  32, 1);
    } else if (idx < WTOT + BTOT) {
        int bi = idx - WTOT;
        float v;
        if      (bi < 128) v = fc1b[bi];
        else if (bi < 256) v = fc1ab[bi - 128];
        else if (bi < 384) v = fc1bb[bi - 256];
        else if (bi < 448) {            // fold fc1c_w[:,128:140] @ w_game into bias
            int n = bi - 384;
            v = fc1cb[n];
            for (int q = 0; q < 12; ++q) v += fc1cw[n * 140 + 128 + q] * wgame[q];
        }
        else if (bi < 480) v = fc2b[bi - 448];
        else if (bi < 512) v = fc3b[bi - 480];
        else if (bi < 640) { int n = bi - 512; v = bih[n] + bhh[n]; }   // fused LSTM bias
        else               v = fc4b[bi - 640];
        wsb[bi] = v;
    }
}

// ---------------------------------------------------------------------------
// Helpers
// ---------------------------------------------------------------------------
__device__ __forceinline__ bf16x8 ld8f(const float* __restrict__ p) {
    f32x4 a = *(const f32x4*)p;
    f32x4 b = *(const f32x4*)(p + 4);
    bf16x8 r;
    r[0] = (__bf16)a[0]; r[1] = (__bf16)a[1]; r[2] = (__bf16)a[2]; r[3] = (__bf16)a[3];
    r[4] = (__bf16)b[0]; r[5] = (__bf16)b[1]; r[6] = (__bf16)b[2]; r[7] = (__bf16)b[3];
    return r;
}

__device__ __forceinline__ bf16x8 ld4f_masked(const float* __restrict__ p, bool on) {
    f32x4 v = {0.f, 0.f, 0.f, 0.f};
    if (on) v = *(const f32x4*)p;
    bf16x8 r;
    r[0] = (__bf16)v[0]; r[1] = (__bf16)v[1]; r[2] = (__bf16)v[2]; r[3] = (__bf16)v[3];
    r[4] = (__bf16)0.f;  r[5] = (__bf16)0.f;  r[6] = (__bf16)0.f;  r[7] = (__bf16)0.f;
    return r;
}

// pack acc[2s],acc[2s+1] (n = 16t+4g+r) into next-layer B-frag, with relu
__device__ __forceinline__ bf16x8 packrelu(const f32x4* a, int s) {
    bf16x8 r;
#pragma unroll
    for (int j = 0; j < 8; ++j) {
        float v = a[2 * s + (j >> 2)][j & 3];
        r[j] = (__bf16)fmaxf(v, 0.f);
    }
    return r;
}

__device__ __forceinline__ float sigm(float v)  { return 1.f / (1.f + __expf(-v)); }
__device__ __forceinline__ float tanh_(float v) { return 1.f - 2.f / (1.f + __expf(2.f * v)); }

// ---------------------------------------------------------------------------
// Fused main kernel: 16 waves/block, ONE 16-row chain per wave, 256 rows/blk
// ---------------------------------------------------------------------------
__global__ __launch_bounds__(1024, 4) void fused_mlp_lstm(
        const float* __restrict__ x,  const float* __restrict__ w,
        const float* __restrict__ h0, const float* __restrict__ c0,
        const float* __restrict__ fc5w, const float* __restrict__ fc5b,
        const __bf16* __restrict__ wsw, const float* __restrict__ wsb,
        float* __restrict__ out) {
    __shared__ __align__(16) __bf16 slds[LDS_ELEMS];   // 144 KB

    const int tid     = threadIdx.x;
    const int lane    = tid & 63;
    const int gq      = lane >> 4;
    const int mr      = lane & 15;
    const int rowbase = blockIdx.x * 256 + (tid >> 6) * 16;
    const int row     = rowbase + mr;

    // ---- stage all big weight layers to LDS (9 x 16B per thread) ----------
    {
        const i32x4* gs = (const i32x4*)wsw;
        i32x4*       sd = (i32x4*)slds;
#pragma unroll
        for (int i = 0; i < 9; ++i) sd[i * 1024 + tid] = gs[i * 1024 + tid];
    }
    __syncthreads();

    const bf16x8* Wfc1  = (const bf16x8*)(slds + WOFF_FC1);
    const bf16x8* Wf1aH = (const bf16x8*)(slds + WOFF_FC1A_H);
    const bf16x8* Wfc1b = (const bf16x8*)(slds + WOFF_FC1B);
    const bf16x8* Wfc1c = (const bf16x8*)(slds + WOFF_FC1C);
    const bf16x8* Wf1aW = (const bf16x8*)(wsw + WOFF_FC1A_W);
    const bf16x8* Wfc2  = (const bf16x8*)(wsw + WOFF_FC2);
    const bf16x8* Wfc3  = (const bf16x8*)(wsw + WOFF_FC3);
    const bf16x8* Wwih  = (const bf16x8*)(wsw + WOFF_WIH);
    const bf16x8* Wwhh  = (const bf16x8*)(wsw + WOFF_WHH);
    const bf16x8* Wfc4  = (const bf16x8*)(wsw + WOFF_FC4);

    // ---- L1: x[256] -> h1[128]  (x pair-streamed, 2 loads in flight) ------
    bf16x8 h1f[4];
    {
        f32x4 acc1[8];
#pragma unroll
        for (int t = 0; t < 8; ++t)
            acc1[t] = *(const f32x4*)(wsb + BOFF_FC1 + 16 * t + 4 * gq);
        const float* xrow = x + row * 256 + 8 * gq;
#pragma unroll
        for (int p = 0; p < 4; ++p) {
            bf16x8 a0 = ld8f(xrow + 64 * p);
            bf16x8 a1 = ld8f(xrow + 64 * p + 32);
#pragma unroll
            for (int t = 0; t < 8; ++t)
                acc1[t] = MFMA16(Wfc1[(t * 8 + 2 * p) * 64 + lane], a0, acc1[t]);
#pragma unroll
            for (int t = 0; t < 8; ++t)
                acc1[t] = MFMA16(Wfc1[(t * 8 + 2 * p + 1) * 64 + lane], a1, acc1[t]);
        }
#pragma unroll
        for (int s = 0; s < 4; ++s) h1f[s] = packrelu(acc1, s);
    }

    // ---- L1a: [h1, w] (128+36) -> h2[128] --------------------------------
    bf16x8 h2f[4];
    {
        bf16x8 wxa0 = ld8f(w + row * 36 + 8 * gq);
        bf16x8 wxa1 = ld4f_masked(w + row * 36 + 32, gq == 0);
        f32x4 acc2[8];
#pragma unroll
        for (int t = 0; t < 8; ++t)
            acc2[t] = *(const f32x4*)(wsb + BOFF_FC1A + 16 * t + 4 * gq);
#pragma unroll
        for (int s = 0; s < 4; ++s)
#pragma unroll
            for (int t = 0; t < 8; ++t)
                acc2[t] = MFMA16(Wf1aH[(t * 4 + s) * 64 + lane], h1f[s], acc2[t]);
#pragma unroll
        for (int t = 0; t < 8; ++t) {
            acc2[t] = MFMA16(Wf1aW[(t * 2 + 0) * 64 + lane], wxa0, acc2[t]);
            acc2[t] = MFMA16(Wf1aW[(t * 2 + 1) * 64 + lane], wxa1, acc2[t]);
        }
#pragma unroll
        for (int s = 0; s < 4; ++s) h2f[s] = packrelu(acc2, s);
    }

    // ---- L1b: h2[128] -> h3[128] -----------------------------------------
    bf16x8 h3f[4];
    {
        f32x4 acc3[8];
#pragma unroll
        for (int t = 0; t < 8; ++t)
            acc3[t] = *(const f32x4*)(wsb + BOFF_FC1B + 16 * t + 4 * gq);
#pragma unroll
        for (int s = 0; s < 4; ++s)
#pragma unroll
            for (int t = 0; t < 8; ++t)
                acc3[t] = MFMA16(Wfc1b[(t * 4 + s) * 64 + lane], h2f[s], acc3[t]);
#pragma unroll
        for (int s = 0; s < 4; ++s) h3f[s] = packrelu(acc3, s);
    }

    // LSTM-state inputs: needed 2 layers from here; issue now
    bf16x8 h0f  = ld8f(h0 + row * 32 + 8 * gq);
    f32x4  c0r0 = *(const f32x4*)(c0 + row * 32 + 4 * gq);
    f32x4  c0r1 = *(const f32x4*)(c0 + row * 32 + 16 + 4 * gq);

    // ---- L1c: [h3, w_game] -> h4[64]  (w_game folded into bias) ----------
    bf16x8 h4f[2];
    {
        f32x4 acc4[4];
#pragma unroll
        for (int t = 0; t < 4; ++t)
            acc4[t] = *(const f32x4*)(wsb + BOFF_FC1C + 16 * t + 4 * gq);
#pragma unroll
        for (int s = 0; s < 4; ++s)
#pragma unroll
            for (int t = 0; t < 4; ++t)
                acc4[t] = MFMA16(Wfc1c[(t * 4 + s) * 64 + lane], h3f[s], acc4[t]);
#pragma unroll
        for (int s = 0; s < 2; ++s) h4f[s] = packrelu(acc4, s);
    }

    // ---- L2: h4[64] -> h5[32] --------------------------------------------
    bf16x8 h5f;
    {
        f32x4 acc5[2];
#pragma unroll
        for (int t = 0; t < 2; ++t)
            acc5[t] = *(const f32x4*)(wsb + BOFF_FC2 + 16 * t + 4 * gq);
#pragma unroll
        for (int s = 0; s < 2; ++s)
#pragma unroll
            for (int t = 0; t < 2; ++t)
                acc5[t] = MFMA16(Wfc2[(t * 2 + s) * 64 + lane], h4f[s], acc5[t]);
        h5f = packrelu(acc5, 0);
    }

    // ---- L3: h5[32] -> h6[32] --------------------------------------------
    bf16x8 h6f;
    {
        f32x4 acc6[2];
#pragma unroll
        for (int t = 0; t < 2; ++t)
            acc6[t] = *(const f32x4*)(wsb + BOFF_FC3 + 16 * t + 4 * gq);
#pragma unroll
        for (int t = 0; t < 2; ++t)
            acc6[t] = MFMA16(Wfc3[t * 64 + lane], h5f, acc6[t]);
        h6f = packrelu(acc6, 0);
    }

    // ---- LSTM gates ------------------------------------------------------
    bf16x8 hnf;
    {
        f32x4 accg[8];
#pragma unroll
        for (int t = 0; t < 8; ++t)
            accg[t] = *(const f32x4*)(wsb + BOFF_LSTM + 16 * t + 4 * gq);
#pragma unroll
        for (int t = 0; t < 8; ++t)
            accg[t] = MFMA16(Wwih[t * 64 + lane], h6f, accg[t]);
#pragma unroll
        for (int t = 0; t < 8; ++t)
            accg[t] = MFMA16(Wwhh[t * 64 + lane], h0f, accg[t]);
        // gate tiles: i -> {0,1}, f -> {2,3}, g -> {4,5}, o -> {6,7}
#pragma unroll
        for (int t2 = 0; t2 < 2; ++t2) {
            f32x4 cc = t2 ? c0r1 : c0r0;
#pragma unroll
            for (int r = 0; r < 4; ++r) {
                float ig = accg[t2][r];
                float fg = accg[2 + t2][r];
                float gg = accg[4 + t2][r];
                float og = accg[6 + t2][r];
                float cn = sigm(fg) * cc[r] + sigm(ig) * tanh_(gg);
                hnf[t2 * 4 + r] = (__bf16)(sigm(og) * tanh_(cn));
            }
        }
    }

    // ---- L4: h_new[32] -> o1[32] -----------------------------------------
    f32x4 acco[2];
#pragma unroll
    for (int t = 0; t < 2; ++t)
        acco[t] = *(const f32x4*)(wsb + BOFF_FC4 + 16 * t + 4 * gq);
#pragma unroll
    for (int t = 0; t < 2; ++t)
        acco[t] = MFMA16(Wfc4[t * 64 + lane], hnf, acco[t]);

    // ---- L5 + sigmoid ----------------------------------------------------
    f32x4 w5a = *(const f32x4*)(fc5w + 4 * gq);
    f32x4 w5b = *(const f32x4*)(fc5w + 16 + 4 * gq);
    float p = 0.f;
#pragma unroll
    for (int r = 0; r < 4; ++r) {
        p += fmaxf(acco[0][r], 0.f) * w5a[r];
        p += fmaxf(acco[1][r], 0.f) * w5b[r];
    }
    p += __shfl_xor(p, 16);
    p += __shfl_xor(p, 32);
    float res = sigm(p + fc5b[0]);
    if (lane < 16) out[rowbase + lane] = res;
}

// ---------------------------------------------------------------------------
extern "C" void kernel_launch(void* const* d_in, const int* in_sizes, int n_in,
                              void* d_out, int out_size, void* d_ws, size_t ws_size,
                              hipStream_t stream) {
    const float* x     = (const float*)d_in[0];
    const float* w     = (const float*)d_in[1];
    const float* h0    = (const float*)d_in[2];
    const float* c0    = (const float*)d_in[3];
    const float* fc1w  = (const float*)d_in[4];
    const float* fc1b  = (const float*)d_in[5];
    const float* fc1aw = (const float*)d_in[6];
    const float* fc1ab = (const float*)d_in[7];
    const float* fc1bw = (const float*)d_in[8];
    const float* fc1bb = (const float*)d_in[9];
    const float* wgame = (const float*)d_in[10];
    const float* fc1cw = (const float*)d_in[11];
    const float* fc1cb = (const float*)d_in[12];
    const float* fc2w  = (const float*)d_in[13];
    const float* fc2b  = (const float*)d_in[14];
    const float* fc3w  = (const float*)d_in[15];
    const float* fc3b  = (const float*)d_in[16];
    const float* wih   = (const float*)d_in[17];
    const float* whh   = (const float*)d_in[18];
    const float* bih   = (const float*)d_in[19];
    const float* bhh   = (const float*)d_in[20];
    const float* fc4w  = (const float*)d_in[21];
    const float* fc4b  = (const float*)d_in[22];
    const float* fc5w  = (const float*)d_in[23];
    const float* fc5b  = (const float*)d_in[24];

    __bf16* wsw = (__bf16*)d_ws;
    float*  wsb = (float*)((char*)d_ws + WTOT * sizeof(__bf16));
    (void)ws_size; (void)n_in; (void)out_size;

    const int Btot = in_sizes[0] / 256;   // 131072 rows

    prep_kernel<<<(WTOT + BTOT + 255) / 256, 256, 0, stream>>>(
        fc1w, fc1b, fc1aw, fc1ab, fc1bw, fc1bb, wgame, fc1cw, fc1cb,
        fc2w, fc2b, fc3w, fc3b, wih, whh, bih, bhh, fc4w, fc4b, wsw, wsb);

    fused_mlp_lstm<<<Btot / 256, 1024, 0, stream>>>(
        x, w, h0, c0, fc5w, fc5b, wsw, wsb, (float*)d_out);
}